// Round 10
// baseline (147.938 us; speedup 1.0000x reference)
//
#include <hip/hip_runtime.h>
#include <hip/hip_bf16.h>

#define T_TOKENS 2048
#define D_EMBD 768
#define N_EXP 64
#define EW 256
#define TOPK 8
#define TW (N_EXP*EW)
#define PAD_SLOTS 20480   // 16384 + 64*63 rounded up to 64-tile granularity
#define SCHED_MAX 2560    // 8 * 320 worst-case positions, mult of 512
#define OUT_BASE (2048*768)

typedef __attribute__((ext_vector_type(8))) short bf16x8;
typedef __attribute__((ext_vector_type(4))) float f32x4;

typedef __attribute__((address_space(1))) void GAS;
typedef __attribute__((address_space(3))) void LAS;
#define GLOAD16(g, l) __builtin_amdgcn_global_load_lds((GAS*)(g), (LAS*)(l), 16, 0, 0)

// ---------------- init ----------------
__global__ void k_init(int* counts, int* cursor, float* psum, float* scal,
                       float* wgt_slot, int* tok_slot, int* sched_e) {
  int i = blockIdx.x*256 + threadIdx.x;   // 20480 threads
  if (i < N_EXP) { counts[i] = 0; cursor[i] = 0; psum[i] = 0.f; }
  if (i < 2) scal[i] = 0.f;
  if (i < PAD_SLOTS) { wgt_slot[i] = 0.f; tok_slot[i] = 0; }
  if (i < SCHED_MAX) sched_e[i] = -1;
}

// ---------------- x -> bf16 ----------------
__global__ void k_cvt_x(const float* __restrict__ x, __hip_bfloat16* __restrict__ xb) {
  int i = blockIdx.x*256 + threadIdx.x;   // 393216 float4
  float4 v = reinterpret_cast<const float4*>(x)[i];
  union { __hip_bfloat16 b; unsigned short u; } c0, c1, c2, c3;
  c0.b = __float2bfloat16(v.x); c1.b = __float2bfloat16(v.y);
  c2.b = __float2bfloat16(v.z); c3.b = __float2bfloat16(v.w);
  ushort4 o; o.x = c0.u; o.y = c1.u; o.z = c2.u; o.w = c3.u;
  reinterpret_cast<ushort4*>(xb)[i] = o;
}

// ---------------- streaming transpose+convert ----------------
// Block owns 64 output rows x (NCH*64) k-slab. Transposed bf16 slab accumulated in
// LDS out-buffer (chunk-XOR swizzle), then written as perfectly contiguous streams.
// Z=0: w1 [768][16384] -> w1t [16384][768]: 256 blocks, slab = full 768-row (96KB contig)
// Z=1: w2 [16384][768] -> w2t [768][16384]: 384 blocks, slab = 64 rows x 512k (1KB/row seg)
template<int Z>
__global__ __launch_bounds__(256) void k_transpose_stream(
    const float* __restrict__ src, __hip_bfloat16* __restrict__ dst) {
  constexpr int NCH   = (Z == 0) ? 12 : 8;      // 64-row k-chunks per slab
  constexpr int ROWCH = NCH*8;                   // 16B units per slab row (96 / 64)
  constexpr int C     = (Z == 0) ? 16384 : 768;  // src row length
  constexpr size_t DL = (Z == 0) ? 768 : 16384;  // dst row length
  __shared__ float tb[64][65];
  __shared__ __hip_bfloat16 ob[64*NCH*64];       // 96 KB / 64 KB

  int bid = blockIdx.x;
  int n0, kbase;
  if (Z == 0) { n0 = bid*64; kbase = 0; }
  else        { n0 = (bid >> 5)*64; kbase = (bid & 31)*512; }

  int tid = threadIdx.x;
  int lr = tid >> 4, lc = (tid & 15)*4;   // load: 16 rows x 16 float4
  int n_l = tid & 63;
  int k8b = (tid >> 6)*2;

  float4 v[4];
  #pragma unroll
  for (int i = 0; i < 4; i++)
    v[i] = *reinterpret_cast<const float4*>(&src[(size_t)(kbase + lr + i*16)*C + n0 + lc]);

  for (int c = 0; c < NCH; c++) {
    __syncthreads();
    #pragma unroll
    for (int i = 0; i < 4; i++) {
      int r = lr + i*16;
      tb[r][lc+0] = v[i].x; tb[r][lc+1] = v[i].y;
      tb[r][lc+2] = v[i].z; tb[r][lc+3] = v[i].w;
    }
    __syncthreads();
    if (c + 1 < NCH) {
      #pragma unroll
      for (int i = 0; i < 4; i++)
        v[i] = *reinterpret_cast<const float4*>(&src[(size_t)(kbase + (c+1)*64 + lr + i*16)*C + n0 + lc]);
    }
    #pragma unroll
    for (int u = 0; u < 2; u++) {
      int k8 = k8b + u;                     // 8-k unit 0..7 within chunk
      unsigned int w[4];
      #pragma unroll
      for (int jj = 0; jj < 4; jj++) {
        union { __hip_bfloat16 b; unsigned short us; } lo, hi;
        lo.b = __float2bfloat16(tb[k8*8 + jj*2][n_l]);
        hi.b = __float2bfloat16(tb[k8*8 + jj*2 + 1][n_l]);
        w[jj] = (unsigned int)lo.us | ((unsigned int)hi.us << 16);
      }
      int chunk = (c*8 + k8) ^ (n_l & 7);   // XOR stays within the chunk's 8-group
      uint4 o = {w[0], w[1], w[2], w[3]};
      *reinterpret_cast<uint4*>(reinterpret_cast<char*>(ob) + (size_t)n_l*(ROWCH*16) + chunk*16) = o;
    }
  }
  __syncthreads();
  // streaming write-out: 4KB per round, fully coalesced
  constexpr int ROUNDS = NCH*2;
  #pragma unroll 4
  for (int r = 0; r < ROUNDS; r++) {
    int f = r*256 + tid;
    int n = f / ROWCH, kc = f % ROWCH;      // constexpr divisor -> magic mul
    uint4 o = *reinterpret_cast<const uint4*>(
        reinterpret_cast<const char*>(ob) + (size_t)n*(ROWCH*16) + ((kc ^ (n & 7))*16));
    *reinterpret_cast<uint4*>(&dst[(size_t)(n0 + n)*DL + kbase + kc*8]) = o;
  }
}

// ---------------- router logits GEMM: lp[kc][t][e] partial sums ----------------
__global__ __launch_bounds__(256) void k_logits(const float* __restrict__ x,
                                                const float* __restrict__ rw,
                                                float* __restrict__ lp) {
  __shared__ float rw_s[8][256];
  int tid = threadIdx.x;
  int tg = blockIdx.x, eg = blockIdx.y, kc = blockIdx.z;
  #pragma unroll
  for (int idx = 0; idx < 8; idx++)
    rw_s[idx][tid] = rw[(size_t)(eg*8 + idx)*D_EMBD + kc*256 + tid];
  __syncthreads();
  int tok = tg*256 + tid;
  const float4* x4 = reinterpret_cast<const float4*>(x + (size_t)tok*D_EMBD + kc*256);
  float acc[8];
  #pragma unroll
  for (int e = 0; e < 8; e++) acc[e] = 0.f;
  #pragma unroll 4
  for (int k4 = 0; k4 < 64; k4++) {
    float4 xv = x4[k4];
    #pragma unroll
    for (int e = 0; e < 8; e++)
      acc[e] += xv.x*rw_s[e][k4*4+0] + xv.y*rw_s[e][k4*4+1]
              + xv.z*rw_s[e][k4*4+2] + xv.w*rw_s[e][k4*4+3];
  }
  float* dst = lp + (size_t)kc*T_TOKENS*N_EXP + (size_t)tok*N_EXP + eg*8;
  float4 o0 = {acc[0], acc[1], acc[2], acc[3]};
  float4 o1 = {acc[4], acc[5], acc[6], acc[7]};
  reinterpret_cast<float4*>(dst)[0] = o0;
  reinterpret_cast<float4*>(dst)[1] = o1;
}

// ---------------- router part 2: sigmoid, parallel-rank top-8, losses ----------------
__global__ __launch_bounds__(256) void k_router2(const float* __restrict__ lp,
                          int* __restrict__ sel_e, float* __restrict__ sel_w,
                          int* __restrict__ counts, float* __restrict__ psum,
                          float* __restrict__ scal) {
  __shared__ float psum_s[4][64];
  __shared__ int cnt_s[4][64];
  int tid = threadIdx.x, wv = tid >> 6, lane = tid & 63;
  float pacc = 0.f, zacc = 0.f;
  int cacc = 0;
  int tbase = blockIdx.x*8 + wv*2;
  #pragma unroll
  for (int it = 0; it < 2; it++) {
    int t = tbase + it;
    float logit = lp[(size_t)t*N_EXP + lane]
                + lp[(size_t)T_TOKENS*N_EXP + (size_t)t*N_EXP + lane]
                + lp[2*(size_t)T_TOKENS*N_EXP + (size_t)t*N_EXP + lane];
    float prob = 1.f/(1.f + expf(-logit));
    pacc += prob;
    float mx = logit;
    for (int s = 32; s; s >>= 1) mx = fmaxf(mx, __shfl_xor(mx, s, 64));
    float sse = expf(logit - mx);
    for (int s = 32; s; s >>= 1) sse += __shfl_xor(sse, s, 64);
    float lse = mx + logf(sse);
    zacc += lse*lse;
    int rank = 0;
    #pragma unroll
    for (int j = 0; j < 64; j++) {
      float pj = __shfl(prob, j, 64);
      rank += (pj > prob || (pj == prob && j < lane)) ? 1 : 0;
    }
    bool sel = rank < TOPK;
    float sp = sel ? prob : 0.f;
    for (int s = 32; s; s >>= 1) sp += __shfl_xor(sp, s, 64);
    if (sel) {
      sel_e[t*TOPK + rank] = lane;
      sel_w[t*TOPK + rank] = prob / (sp + 1e-20f);
      cacc++;
    }
  }
  psum_s[wv][lane] = pacc;
  cnt_s[wv][lane] = cacc;
  if (lane == 0) atomicAdd(&scal[0], zacc);
  __syncthreads();
  if (tid < 64) {
    float p = psum_s[0][tid] + psum_s[1][tid] + psum_s[2][tid] + psum_s[3][tid];
    int c = cnt_s[0][tid] + cnt_s[1][tid] + cnt_s[2][tid] + cnt_s[3][tid];
    atomicAdd(&psum[tid], p);
    atomicAdd(&counts[tid], c);
  }
}

// ---------------- schedule: 64-row tiles, XCD-grouped positions ----------------
__global__ void k_schedule(const int* __restrict__ counts, int* __restrict__ offsets,
                           int* __restrict__ sched_e, int* __restrict__ sched_r0) {
  int e = threadIdx.x;   // 64 threads, one wave
  int c = counts[e];
  int tiles = (c + 63) >> 6;
  int padded = tiles << 6;
  int ip = padded;
  for (int s = 1; s < 64; s <<= 1) { int v = __shfl_up(ip, s, 64); if (e >= s) ip += v; }
  int rowoff = ip - padded;
  offsets[e] = rowoff;
  int it = tiles;
  for (int s = 8; s < 64; s <<= 1) { int v = __shfl_up(it, s, 64); if (e >= s) it += v; }
  int rank = it - tiles;
  int xcd = e & 7;
  for (int i = 0; i < tiles; i++) {
    int p = xcd + 8*(rank + i);
    sched_e[p] = e;
    sched_r0[p] = rowoff + i*64;
  }
}

// ---------------- assign tokens to slots ----------------
__global__ void k_assign(const int* __restrict__ sel_e, const float* __restrict__ sel_w,
                         const int* __restrict__ offsets, int* __restrict__ cursor,
                         int* __restrict__ tok_slot, float* __restrict__ wgt_slot,
                         int* __restrict__ slot_tk) {
  int i = blockIdx.x*256 + threadIdx.x;   // 16384
  int e = sel_e[i];
  int pos = atomicAdd(&cursor[e], 1);
  int slot = offsets[e] + pos;
  tok_slot[slot] = i >> 3;
  wgt_slot[slot] = sel_w[i];
  slot_tk[i] = slot;
}

// ---------------- grouped GEMM, 64x128 tile, BK=64, double-buffered 2-phase ----------------
// MODE 1: h[slot][:] = relu(x[tok] @ W1_e)^2 * gate   (K=768, N=256 via 2 n-chunks)
// MODE 2: y[slot][:] = h[slot][:] @ W2_e              (K=256, N=768 via 6 n-chunks, bf16 store)
template<int MODE>
__global__ __launch_bounds__(256) void k_moe_gemm(
    const __hip_bfloat16* __restrict__ Ab, const __hip_bfloat16* __restrict__ Bt,
    const int* __restrict__ sched_e, const int* __restrict__ sched_r0,
    const int* __restrict__ tok_slot, const float* __restrict__ wgt_slot,
    __hip_bfloat16* __restrict__ outp) {
  constexpr int NS = (MODE == 1) ? 12 : 4;   // K-steps of 64
  __shared__ __hip_bfloat16 As[2][64*64];
  __shared__ __hip_bfloat16 Bs[2][128*64];
  int tid = threadIdx.x;
  int nch = blockIdx.y;
  int arl = tid >> 3, akc = tid & 7;
  int a_off = ((akc ^ (arl & 7)) << 3);
  int b_off = a_off;
  int wv = tid >> 6, lane = tid & 63;
  int wm = wv >> 1, wn = wv & 1;
  int l15 = lane & 15, l4 = lane >> 4;
  int b_str = (MODE == 1) ? D_EMBD : TW;

  for (int p = blockIdx.x; p < SCHED_MAX; p += gridDim.x) {
    int e = sched_e[p];
    if (e < 0) continue;
    int r0 = sched_r0[p];

    size_t a_base0, a_base1;
    if (MODE == 1) {
      a_base0 = (size_t)tok_slot[r0 + arl] * D_EMBD;
      a_base1 = (size_t)tok_slot[r0 + arl + 32] * D_EMBD;
    } else {
      a_base0 = (size_t)(r0 + arl) * EW;
      a_base1 = (size_t)(r0 + arl + 32) * EW;
    }
    size_t b_base = (MODE == 1) ? (size_t)(e*EW + nch*128) * D_EMBD
                                : (size_t)(nch*128) * TW + (size_t)e*EW;

    f32x4 acc[2][4];
    f32x4 z = {0.f, 0.f, 0.f, 0.f};
    #pragma unroll
    for (int m = 0; m < 2; m++)
      #pragma unroll
      for (int n = 0; n < 4; n++) acc[m][n] = z;

    auto STAGE = [&](int bsel, int k0) {
      GLOAD16(Ab + a_base0 + k0 + a_off, &As[bsel][0] + tid*8);
      GLOAD16(Ab + a_base1 + k0 + a_off, &As[bsel][0] + (256 + tid)*8);
      #pragma unroll
      for (int i = 0; i < 4; i++) {
        int br = i*32 + arl;
        GLOAD16(Bt + b_base + (size_t)br*b_str + k0 + b_off, &Bs[bsel][0] + (i*256 + tid)*8);
      }
    };

    int cur = 0;
    STAGE(0, 0);
    asm volatile("s_waitcnt vmcnt(0)" ::: "memory");
    __syncthreads();
    for (int step = 0; step < NS; step++) {
      if (step + 1 < NS) STAGE(cur ^ 1, (step + 1)*64);
      const bf16x8* A8 = reinterpret_cast<const bf16x8*>(&As[cur][0]);
      const bf16x8* B8 = reinterpret_cast<const bf16x8*>(&Bs[cur][0]);
      bf16x8 af[2][2], bq[4][2];
      #pragma unroll
      for (int m = 0; m < 2; m++) {
        int ra = wm*32 + m*16 + l15;
        #pragma unroll
        for (int kk = 0; kk < 2; kk++)
          af[m][kk] = A8[ra*8 + ((kk*4 + l4) ^ (ra & 7))];
      }
      #pragma unroll
      for (int n = 0; n < 4; n++) {
        int rb = wn*64 + n*16 + l15;
        #pragma unroll
        for (int kk = 0; kk < 2; kk++)
          bq[n][kk] = B8[rb*8 + ((kk*4 + l4) ^ (rb & 7))];
      }
      #pragma unroll
      for (int kk = 0; kk < 2; kk++)
        #pragma unroll
        for (int m = 0; m < 2; m++)
          #pragma unroll
          for (int n = 0; n < 4; n++)
            acc[m][n] = __builtin_amdgcn_mfma_f32_16x16x32_bf16(af[m][kk], bq[n][kk], acc[m][n], 0, 0, 0);
      asm volatile("s_waitcnt vmcnt(0)" ::: "memory");
      __syncthreads();
      cur ^= 1;
    }

    if (MODE == 1) {
      #pragma unroll
      for (int m = 0; m < 2; m++)
        #pragma unroll
        for (int j = 0; j < 4; j++) {
          int r = r0 + wm*32 + m*16 + l4*4 + j;
          float wg = wgt_slot[r];
          #pragma unroll
          for (int n = 0; n < 4; n++) {
            int col = nch*128 + wn*64 + n*16 + l15;
            float v = fmaxf(acc[m][n][j], 0.f);
            outp[(size_t)r*EW + col] = __float2bfloat16(v*v*wg);
          }
        }
    } else {
      #pragma unroll
      for (int m = 0; m < 2; m++)
        #pragma unroll
        for (int j = 0; j < 4; j++) {
          int r = r0 + wm*32 + m*16 + l4*4 + j;
          #pragma unroll
          for (int n = 0; n < 4; n++) {
            int col = nch*128 + wn*64 + n*16 + l15;
            outp[(size_t)r*D_EMBD + col] = __float2bfloat16(acc[m][n][j]);
          }
        }
    }
  }
}

// ---------------- combine 8 expert rows per token (vectorized gather) ----------------
__global__ void k_combine(const __hip_bfloat16* __restrict__ y, const int* __restrict__ slot_tk,
                          float* __restrict__ out) {
  __shared__ int s[TOPK];
  int t = blockIdx.x, tid = threadIdx.x;
  if (tid < TOPK) s[tid] = slot_tk[t*TOPK + tid];
  __syncthreads();
  if (tid < 192) {
    int c = tid*4;
    float a0 = 0.f, a1 = 0.f, a2 = 0.f, a3 = 0.f;
    #pragma unroll
    for (int k = 0; k < TOPK; k++) {
      ushort4 v = *reinterpret_cast<const ushort4*>(&y[(size_t)s[k]*D_EMBD + c]);
      union { unsigned int u; float f; } f0, f1, f2, f3;
      f0.u = ((unsigned int)v.x) << 16;
      f1.u = ((unsigned int)v.y) << 16;
      f2.u = ((unsigned int)v.z) << 16;
      f3.u = ((unsigned int)v.w) << 16;
      a0 += f0.f; a1 += f1.f; a2 += f2.f; a3 += f3.f;
    }
    float4 o = {a0, a1, a2, a3};
    *reinterpret_cast<float4*>(&out[(size_t)t*D_EMBD + c]) = o;
  }
}

// ---------------- aux losses + f_i ----------------
__global__ void k_finalize(const int* __restrict__ counts, const float* __restrict__ psum,
                           const float* __restrict__ scal, float* __restrict__ out) {
  __shared__ float part[N_EXP], ptot[N_EXP];
  int e = threadIdx.x;
  float f = (float)counts[e] / 16384.f;
  float p = psum[e] / 2048.f;
  part[e] = f * p;
  ptot[e] = p;
  out[OUT_BASE + 3 + e] = f;
  __syncthreads();
  if (e == 0) {
    float s = 0.f, q = 0.f;
    for (int i = 0; i < N_EXP; i++) { s += part[i]; q += ptot[i]; }
    out[OUT_BASE + 0] = scal[0] / 2048.f;      // router_z_loss
    out[OUT_BASE + 1] = 64.f * s;              // load_balance_loss
    out[OUT_BASE + 2] = q;                     // compute_loss
  }
}

extern "C" void kernel_launch(void* const* d_in, const int* in_sizes, int n_in,
                              void* d_out, int out_size, void* d_ws, size_t ws_size,
                              hipStream_t stream) {
  const float* x  = (const float*)d_in[0];
  const float* rw = (const float*)d_in[1];
  const float* w1 = (const float*)d_in[2];
  const float* w2 = (const float*)d_in[3];
  float* out = (float*)d_out;
  char* ws = (char*)d_ws;

  size_t o = 0;
  auto alloc = [&](size_t b) { size_t r = o; o += (b + 255) & ~(size_t)255; return r; };
  __hip_bfloat16* xb    = (__hip_bfloat16*)(ws + alloc(2048UL*768*2));
  __hip_bfloat16* w1t   = (__hip_bfloat16*)(ws + alloc(16384UL*768*2));
  __hip_bfloat16* w2t   = (__hip_bfloat16*)(ws + alloc(768UL*16384*2));
  __hip_bfloat16* hprm  = (__hip_bfloat16*)(ws + alloc((size_t)PAD_SLOTS*256*2));
  __hip_bfloat16* yprm  = (__hip_bfloat16*)(ws + alloc((size_t)PAD_SLOTS*768*2));
  float* lp      = (float*)(ws + alloc(3UL*2048*64*4));
  int*   sel_e   = (int*)  (ws + alloc(16384UL*4));
  float* sel_w   = (float*)(ws + alloc(16384UL*4));
  int*   slot_tk = (int*)  (ws + alloc(16384UL*4));
  int*   tokslot = (int*)  (ws + alloc((size_t)PAD_SLOTS*4));
  float* wgtslot = (float*)(ws + alloc((size_t)PAD_SLOTS*4));
  int*   counts  = (int*)  (ws + alloc(256));
  int*   cursor  = (int*)  (ws + alloc(256));
  float* psum    = (float*)(ws + alloc(256));
  float* scal    = (float*)(ws + alloc(256));
  int*   offsets = (int*)  (ws + alloc(256));
  int*   sch_e   = (int*)  (ws + alloc(SCHED_MAX*4));
  int*   sch_r0  = (int*)  (ws + alloc(SCHED_MAX*4));

  k_init<<<80, 256, 0, stream>>>(counts, cursor, psum, scal, wgtslot, tokslot, sch_e);
  k_cvt_x<<<1536, 256, 0, stream>>>(x, xb);
  k_transpose_stream<0><<<256, 256, 0, stream>>>(w1, w1t);
  k_transpose_stream<1><<<384, 256, 0, stream>>>(w2, w2t);
  k_logits<<<dim3(8, 8, 3), 256, 0, stream>>>(x, rw, lp);
  k_router2<<<256, 256, 0, stream>>>(lp, sel_e, sel_w, counts, psum, scal);
  k_schedule<<<1, 64, 0, stream>>>(counts, offsets, sch_e, sch_r0);
  k_assign<<<64, 256, 0, stream>>>(sel_e, sel_w, offsets, cursor, tokslot, wgtslot, slot_tk);
  k_moe_gemm<1><<<dim3(512, 2), 256, 0, stream>>>(xb, w1t, sch_e, sch_r0, tokslot, wgtslot, hprm);
  k_moe_gemm<2><<<dim3(512, 6), 256, 0, stream>>>(hprm, w2t, sch_e, sch_r0, tokslot, wgtslot, yprm);
  k_combine<<<2048, 256, 0, stream>>>(yprm, slot_tk, out);
  k_finalize<<<1, 64, 0, stream>>>(counts, psum, scal, out);
}

// Round 11
// 143.827 us; speedup vs baseline: 1.0286x; 1.0286x over previous
//
#include <hip/hip_runtime.h>
#include <hip/hip_bf16.h>

#define T_TOKENS 2048
#define D_EMBD 768
#define N_EXP 64
#define EW 256
#define TOPK 8
#define TW (N_EXP*EW)
#define PAD_SLOTS 20480   // 16384 + 64*63 rounded up to 64-tile granularity
#define SCHED_MAX 2560    // 8 * 320 worst-case positions, mult of 512
#define OUT_BASE (2048*768)

typedef __attribute__((ext_vector_type(8))) short bf16x8;
typedef __attribute__((ext_vector_type(4))) float f32x4;

typedef __attribute__((address_space(1))) void GAS;
typedef __attribute__((address_space(3))) void LAS;
#define GLOAD16(g, l) __builtin_amdgcn_global_load_lds((GAS*)(g), (LAS*)(l), 16, 0, 0)

__device__ inline unsigned short f2bu(float f) {
  union { __hip_bfloat16 b; unsigned short u; } cv; cv.b = __float2bfloat16(f); return cv.u;
}
__device__ inline unsigned int pk2(float a, float b) {
  return (unsigned int)f2bu(a) | ((unsigned int)f2bu(b) << 16);
}

// ---------------- init ----------------
__global__ void k_init(int* counts, int* cursor, float* psum, float* scal,
                       float* wgt_slot, int* tok_slot, int* sched_e) {
  int i = blockIdx.x*256 + threadIdx.x;   // 20480 threads
  if (i < N_EXP) { counts[i] = 0; cursor[i] = 0; psum[i] = 0.f; }
  if (i < 2) scal[i] = 0.f;
  if (i < PAD_SLOTS) { wgt_slot[i] = 0.f; tok_slot[i] = 0; }
  if (i < SCHED_MAX) sched_e[i] = -1;
}

// ---------------- router logits GEMM: lp[kc][t][e] partial sums ----------------
__global__ __launch_bounds__(256) void k_logits(const float* __restrict__ x,
                                                const float* __restrict__ rw,
                                                float* __restrict__ lp) {
  __shared__ float rw_s[8][256];
  int tid = threadIdx.x;
  int tg = blockIdx.x, eg = blockIdx.y, kc = blockIdx.z;
  #pragma unroll
  for (int idx = 0; idx < 8; idx++)
    rw_s[idx][tid] = rw[(size_t)(eg*8 + idx)*D_EMBD + kc*256 + tid];
  __syncthreads();
  int tok = tg*256 + tid;
  const float4* x4 = reinterpret_cast<const float4*>(x + (size_t)tok*D_EMBD + kc*256);
  float acc[8];
  #pragma unroll
  for (int e = 0; e < 8; e++) acc[e] = 0.f;
  #pragma unroll 4
  for (int k4 = 0; k4 < 64; k4++) {
    float4 xv = x4[k4];
    #pragma unroll
    for (int e = 0; e < 8; e++)
      acc[e] += xv.x*rw_s[e][k4*4+0] + xv.y*rw_s[e][k4*4+1]
              + xv.z*rw_s[e][k4*4+2] + xv.w*rw_s[e][k4*4+3];
  }
  float* dst = lp + (size_t)kc*T_TOKENS*N_EXP + (size_t)tok*N_EXP + eg*8;
  float4 o0 = {acc[0], acc[1], acc[2], acc[3]};
  float4 o1 = {acc[4], acc[5], acc[6], acc[7]};
  reinterpret_cast<float4*>(dst)[0] = o0;
  reinterpret_cast<float4*>(dst)[1] = o1;
}

// ---------------- router part 2: sigmoid, parallel-rank top-8, losses ----------------
__global__ __launch_bounds__(256) void k_router2(const float* __restrict__ lp,
                          int* __restrict__ sel_e, float* __restrict__ sel_w,
                          int* __restrict__ counts, float* __restrict__ psum,
                          float* __restrict__ scal) {
  __shared__ float psum_s[4][64];
  __shared__ int cnt_s[4][64];
  int tid = threadIdx.x, wv = tid >> 6, lane = tid & 63;
  float pacc = 0.f, zacc = 0.f;
  int cacc = 0;
  int tbase = blockIdx.x*8 + wv*2;
  #pragma unroll
  for (int it = 0; it < 2; it++) {
    int t = tbase + it;
    float logit = lp[(size_t)t*N_EXP + lane]
                + lp[(size_t)T_TOKENS*N_EXP + (size_t)t*N_EXP + lane]
                + lp[2*(size_t)T_TOKENS*N_EXP + (size_t)t*N_EXP + lane];
    float prob = 1.f/(1.f + expf(-logit));
    pacc += prob;
    float mx = logit;
    for (int s = 32; s; s >>= 1) mx = fmaxf(mx, __shfl_xor(mx, s, 64));
    float sse = expf(logit - mx);
    for (int s = 32; s; s >>= 1) sse += __shfl_xor(sse, s, 64);
    float lse = mx + logf(sse);
    zacc += lse*lse;
    int rank = 0;
    #pragma unroll
    for (int j = 0; j < 64; j++) {
      float pj = __shfl(prob, j, 64);
      rank += (pj > prob || (pj == prob && j < lane)) ? 1 : 0;
    }
    bool sel = rank < TOPK;
    float sp = sel ? prob : 0.f;
    for (int s = 32; s; s >>= 1) sp += __shfl_xor(sp, s, 64);
    if (sel) {
      sel_e[t*TOPK + rank] = lane;
      sel_w[t*TOPK + rank] = prob / (sp + 1e-20f);
      cacc++;
    }
  }
  psum_s[wv][lane] = pacc;
  cnt_s[wv][lane] = cacc;
  if (lane == 0) atomicAdd(&scal[0], zacc);
  __syncthreads();
  if (tid < 64) {
    float p = psum_s[0][tid] + psum_s[1][tid] + psum_s[2][tid] + psum_s[3][tid];
    int c = cnt_s[0][tid] + cnt_s[1][tid] + cnt_s[2][tid] + cnt_s[3][tid];
    atomicAdd(&psum[tid], p);
    atomicAdd(&counts[tid], c);
  }
}

// ---------------- schedule: 64-row tiles, XCD-grouped positions ----------------
__global__ void k_schedule(const int* __restrict__ counts, int* __restrict__ offsets,
                           int* __restrict__ sched_e, int* __restrict__ sched_r0) {
  int e = threadIdx.x;   // 64 threads, one wave
  int c = counts[e];
  int tiles = (c + 63) >> 6;
  int padded = tiles << 6;
  int ip = padded;
  for (int s = 1; s < 64; s <<= 1) { int v = __shfl_up(ip, s, 64); if (e >= s) ip += v; }
  int rowoff = ip - padded;
  offsets[e] = rowoff;
  int it = tiles;
  for (int s = 8; s < 64; s <<= 1) { int v = __shfl_up(it, s, 64); if (e >= s) it += v; }
  int rank = it - tiles;
  int xcd = e & 7;
  for (int i = 0; i < tiles; i++) {
    int p = xcd + 8*(rank + i);
    sched_e[p] = e;
    sched_r0[p] = rowoff + i*64;
  }
}

// ---------------- assign tokens to slots ----------------
__global__ void k_assign(const int* __restrict__ sel_e, const float* __restrict__ sel_w,
                         const int* __restrict__ offsets, int* __restrict__ cursor,
                         int* __restrict__ tok_slot, float* __restrict__ wgt_slot,
                         int* __restrict__ slot_tk) {
  int i = blockIdx.x*256 + threadIdx.x;   // 16384
  int e = sel_e[i];
  int pos = atomicAdd(&cursor[e], 1);
  int slot = offsets[e] + pos;
  tok_slot[slot] = i >> 3;
  wgt_slot[slot] = sel_w[i];
  slot_tk[i] = slot;
}

// ---------------- grouped GEMM with fused fp32->bf16 convert+transpose staging ----------------
// 64x128 tile, BK=64, double-buffered.
// MODE 1: A = x fp32 (gathered rows, reg-staged+cvt), B = w1 fp32 native [768][16384]
//         out: h[slot] = relu(x@W1_e)^2 * gate  (K=768, 12 steps, grid (512,2))
// MODE 2: A = hprm bf16 (global_load_lds), B = w2 fp32 native [16384][768]
//         out: y[slot] = h@W2_e                 (K=256, 4 steps, grid (512,6))
// B staging transposes in-LDS: pair-row loads -> packed bf16 k-pairs -> b32 writes,
// chunk swizzle S(n) = (n&7)^((n>>3)&7); A layout keeps old XOR(m&7) chunk swizzle.
template<int MODE>
__global__ __launch_bounds__(256) void k_moe_gemm(
    const void* __restrict__ Asrc, const float* __restrict__ Bsrc,
    const int* __restrict__ sched_e, const int* __restrict__ sched_r0,
    const int* __restrict__ tok_slot, const float* __restrict__ wgt_slot,
    __hip_bfloat16* __restrict__ outp) {
  constexpr int NS   = (MODE == 1) ? 12 : 4;       // K-steps of 64
  constexpr int BSTR = (MODE == 1) ? TW : D_EMBD;  // native B row stride (fp32)
  __shared__ __hip_bfloat16 As[2][64*64];
  __shared__ __hip_bfloat16 Bs[2][128*64];
  int tid = threadIdx.x;
  int nch = blockIdx.y;
  // B staging lanes: n4 = col-quad (coalesced), kpb = k-pair base
  int n4 = tid & 31, kpb = tid >> 5;
  // A staging lanes (MODE1): mrow 0..15, k4f = k-quad
  int mrow = tid >> 4, k4f = tid & 15;
  // MODE2 A gload lanes:
  int arl = tid >> 3, akc = tid & 7;
  int a_off = ((akc ^ (arl & 7)) << 3);
  int wv = tid >> 6, lane = tid & 63;
  int wm = wv >> 1, wn = wv & 1;
  int l15 = lane & 15, l4 = lane >> 4;

  for (int p = blockIdx.x; p < SCHED_MAX; p += gridDim.x) {
    int e = sched_e[p];
    if (e < 0) continue;
    int r0 = sched_r0[p];

    int browb = (MODE == 1) ? 0 : e*EW;                    // B k-row base
    int bcolb = (MODE == 1) ? (e*EW + nch*128) : nch*128;  // B col base

    // MODE1 A gather bases; MODE2 gload bases
    int tks[4];
    size_t a_base0 = 0, a_base1 = 0;
    if (MODE == 1) {
      #pragma unroll
      for (int i = 0; i < 4; i++) tks[i] = tok_slot[r0 + i*16 + mrow];
    } else {
      a_base0 = (size_t)(r0 + arl) * EW;
      a_base1 = (size_t)(r0 + arl + 32) * EW;
    }

    float bv0[4][4], bv1[4][4], av[4][4];

    auto B_LOAD = [&](int k0) {
      #pragma unroll
      for (int j = 0; j < 4; j++) {
        const float* rp = Bsrc + (size_t)(browb + k0 + 2*(kpb + 8*j))*BSTR + bcolb + n4*4;
        *reinterpret_cast<float4*>(&bv0[j][0]) = *reinterpret_cast<const float4*>(rp);
        *reinterpret_cast<float4*>(&bv1[j][0]) = *reinterpret_cast<const float4*>(rp + BSTR);
      }
    };
    auto B_WRITE = [&](int bsel) {
      char* bs = (char*)&Bs[bsel][0];
      #pragma unroll
      for (int j = 0; j < 4; j++) {
        int kp = kpb + 8*j;
        #pragma unroll
        for (int c = 0; c < 4; c++) {
          int n = n4*4 + c;
          int ch = (kp >> 2) ^ ((n & 7) ^ ((n >> 3) & 7));
          *reinterpret_cast<unsigned int*>(bs + n*128 + ch*16 + (kp & 3)*4)
              = pk2(bv0[j][c], bv1[j][c]);
        }
      }
    };
    auto A_LOAD1 = [&](int k0) {
      const float* xf = (const float*)Asrc;
      #pragma unroll
      for (int i = 0; i < 4; i++)
        *reinterpret_cast<float4*>(&av[i][0]) =
            *reinterpret_cast<const float4*>(xf + (size_t)tks[i]*D_EMBD + k0 + k4f*4);
    };
    auto A_WRITE1 = [&](int bsel) {
      char* as_ = (char*)&As[bsel][0];
      #pragma unroll
      for (int i = 0; i < 4; i++) {
        int m = i*16 + mrow;
        int ch = (k4f >> 1) ^ (m & 7);
        uint2 val = { pk2(av[i][0], av[i][1]), pk2(av[i][2], av[i][3]) };
        *reinterpret_cast<uint2*>(as_ + m*128 + ch*16 + (k4f & 1)*8) = val;
      }
    };
    auto A_GLOAD2 = [&](int bsel, int k0) {
      const __hip_bfloat16* hb = (const __hip_bfloat16*)Asrc;
      GLOAD16(hb + a_base0 + k0 + a_off, &As[bsel][0] + tid*8);
      GLOAD16(hb + a_base1 + k0 + a_off, &As[bsel][0] + (256 + tid)*8);
    };

    f32x4 acc[2][4];
    f32x4 z = {0.f, 0.f, 0.f, 0.f};
    #pragma unroll
    for (int m = 0; m < 2; m++)
      #pragma unroll
      for (int n = 0; n < 4; n++) acc[m][n] = z;

    // prologue: stage step 0 into buf 0
    if (MODE == 1) { A_LOAD1(0); B_LOAD(0); A_WRITE1(0); B_WRITE(0); }
    else           { A_GLOAD2(0, 0); B_LOAD(0); B_WRITE(0);
                     asm volatile("s_waitcnt vmcnt(0)" ::: "memory"); }
    __syncthreads();

    int cur = 0;
    for (int step = 0; step < NS; step++) {
      bool more = (step + 1 < NS);
      int k1 = (step + 1)*64;
      // issue next-step loads early (latency hides under frag reads + MFMA)
      if (more) {
        if (MODE == 1) { A_LOAD1(k1); B_LOAD(k1); }
        else           { A_GLOAD2(cur ^ 1, k1); B_LOAD(k1); }
      }
      const char* asC = (const char*)&As[cur][0];
      const char* bsC = (const char*)&Bs[cur][0];
      bf16x8 af[2][2], bq[4][2];
      #pragma unroll
      for (int m = 0; m < 2; m++) {
        int ra = wm*32 + m*16 + l15;
        #pragma unroll
        for (int kk = 0; kk < 2; kk++)
          af[m][kk] = *reinterpret_cast<const bf16x8*>(
              asC + ra*128 + (((kk*4 + l4) ^ (ra & 7)) << 4));
      }
      #pragma unroll
      for (int n = 0; n < 4; n++) {
        int rb = wn*64 + n*16 + l15;
        int Sb = (rb & 7) ^ ((rb >> 3) & 7);
        #pragma unroll
        for (int kk = 0; kk < 2; kk++)
          bq[n][kk] = *reinterpret_cast<const bf16x8*>(
              bsC + rb*128 + (((kk*4 + l4) ^ Sb) << 4));
      }
      #pragma unroll
      for (int kk = 0; kk < 2; kk++)
        #pragma unroll
        for (int m = 0; m < 2; m++)
          #pragma unroll
          for (int n = 0; n < 4; n++)
            acc[m][n] = __builtin_amdgcn_mfma_f32_16x16x32_bf16(af[m][kk], bq[n][kk], acc[m][n], 0, 0, 0);
      if (more) {
        if (MODE == 1) { A_WRITE1(cur ^ 1); B_WRITE(cur ^ 1); }
        else           { B_WRITE(cur ^ 1);
                         asm volatile("s_waitcnt vmcnt(0)" ::: "memory"); }
      }
      __syncthreads();
      cur ^= 1;
    }

    if (MODE == 1) {
      #pragma unroll
      for (int m = 0; m < 2; m++)
        #pragma unroll
        for (int j = 0; j < 4; j++) {
          int r = r0 + wm*32 + m*16 + l4*4 + j;
          float wg = wgt_slot[r];
          #pragma unroll
          for (int n = 0; n < 4; n++) {
            int col = nch*128 + wn*64 + n*16 + l15;
            float v = fmaxf(acc[m][n][j], 0.f);
            outp[(size_t)r*EW + col] = __float2bfloat16(v*v*wg);
          }
        }
    } else {
      #pragma unroll
      for (int m = 0; m < 2; m++)
        #pragma unroll
        for (int j = 0; j < 4; j++) {
          int r = r0 + wm*32 + m*16 + l4*4 + j;
          #pragma unroll
          for (int n = 0; n < 4; n++) {
            int col = nch*128 + wn*64 + n*16 + l15;
            outp[(size_t)r*D_EMBD + col] = __float2bfloat16(acc[m][n][j]);
          }
        }
    }
  }
}

// ---------------- combine 8 expert rows per token (vectorized gather) ----------------
__global__ void k_combine(const __hip_bfloat16* __restrict__ y, const int* __restrict__ slot_tk,
                          float* __restrict__ out) {
  __shared__ int s[TOPK];
  int t = blockIdx.x, tid = threadIdx.x;
  if (tid < TOPK) s[tid] = slot_tk[t*TOPK + tid];
  __syncthreads();
  if (tid < 192) {
    int c = tid*4;
    float a0 = 0.f, a1 = 0.f, a2 = 0.f, a3 = 0.f;
    #pragma unroll
    for (int k = 0; k < TOPK; k++) {
      ushort4 v = *reinterpret_cast<const ushort4*>(&y[(size_t)s[k]*D_EMBD + c]);
      union { unsigned int u; float f; } f0, f1, f2, f3;
      f0.u = ((unsigned int)v.x) << 16;
      f1.u = ((unsigned int)v.y) << 16;
      f2.u = ((unsigned int)v.z) << 16;
      f3.u = ((unsigned int)v.w) << 16;
      a0 += f0.f; a1 += f1.f; a2 += f2.f; a3 += f3.f;
    }
    float4 o = {a0, a1, a2, a3};
    *reinterpret_cast<float4*>(&out[(size_t)t*D_EMBD + c]) = o;
  }
}

// ---------------- aux losses + f_i ----------------
__global__ void k_finalize(const int* __restrict__ counts, const float* __restrict__ psum,
                           const float* __restrict__ scal, float* __restrict__ out) {
  __shared__ float part[N_EXP], ptot[N_EXP];
  int e = threadIdx.x;
  float f = (float)counts[e] / 16384.f;
  float p = psum[e] / 2048.f;
  part[e] = f * p;
  ptot[e] = p;
  out[OUT_BASE + 3 + e] = f;
  __syncthreads();
  if (e == 0) {
    float s = 0.f, q = 0.f;
    for (int i = 0; i < N_EXP; i++) { s += part[i]; q += ptot[i]; }
    out[OUT_BASE + 0] = scal[0] / 2048.f;      // router_z_loss
    out[OUT_BASE + 1] = 64.f * s;              // load_balance_loss
    out[OUT_BASE + 2] = q;                     // compute_loss
  }
}

extern "C" void kernel_launch(void* const* d_in, const int* in_sizes, int n_in,
                              void* d_out, int out_size, void* d_ws, size_t ws_size,
                              hipStream_t stream) {
  const float* x  = (const float*)d_in[0];
  const float* rw = (const float*)d_in[1];
  const float* w1 = (const float*)d_in[2];
  const float* w2 = (const float*)d_in[3];
  float* out = (float*)d_out;
  char* ws = (char*)d_ws;

  size_t o = 0;
  auto alloc = [&](size_t b) { size_t r = o; o += (b + 255) & ~(size_t)255; return r; };
  __hip_bfloat16* hprm  = (__hip_bfloat16*)(ws + alloc((size_t)PAD_SLOTS*256*2));
  __hip_bfloat16* yprm  = (__hip_bfloat16*)(ws + alloc((size_t)PAD_SLOTS*768*2));
  float* lp      = (float*)(ws + alloc(3UL*2048*64*4));
  int*   sel_e   = (int*)  (ws + alloc(16384UL*4));
  float* sel_w   = (float*)(ws + alloc(16384UL*4));
  int*   slot_tk = (int*)  (ws + alloc(16384UL*4));
  int*   tokslot = (int*)  (ws + alloc((size_t)PAD_SLOTS*4));
  float* wgtslot = (float*)(ws + alloc((size_t)PAD_SLOTS*4));
  int*   counts  = (int*)  (ws + alloc(256));
  int*   cursor  = (int*)  (ws + alloc(256));
  float* psum    = (float*)(ws + alloc(256));
  float* scal    = (float*)(ws + alloc(256));
  int*   offsets = (int*)  (ws + alloc(256));
  int*   sch_e   = (int*)  (ws + alloc(SCHED_MAX*4));
  int*   sch_r0  = (int*)  (ws + alloc(SCHED_MAX*4));

  k_init<<<80, 256, 0, stream>>>(counts, cursor, psum, scal, wgtslot, tokslot, sch_e);
  k_logits<<<dim3(8, 8, 3), 256, 0, stream>>>(x, rw, lp);
  k_router2<<<256, 256, 0, stream>>>(lp, sel_e, sel_w, counts, psum, scal);
  k_schedule<<<1, 64, 0, stream>>>(counts, offsets, sch_e, sch_r0);
  k_assign<<<64, 256, 0, stream>>>(sel_e, sel_w, offsets, cursor, tokslot, wgtslot, slot_tk);
  k_moe_gemm<1><<<dim3(512, 2), 256, 0, stream>>>((const void*)x, w1, sch_e, sch_r0, tokslot, wgtslot, hprm);
  k_moe_gemm<2><<<dim3(512, 6), 256, 0, stream>>>((const void*)hprm, w2, sch_e, sch_r0, tokslot, wgtslot, yprm);
  k_combine<<<2048, 256, 0, stream>>>(yprm, slot_tk, out);
  k_finalize<<<1, 64, 0, stream>>>(counts, psum, scal, out);
}

// Round 12
// 142.269 us; speedup vs baseline: 1.0398x; 1.0110x over previous
//
#include <hip/hip_runtime.h>
#include <hip/hip_bf16.h>

#define T_TOKENS 2048
#define D_EMBD 768
#define N_EXP 64
#define EW 256
#define TOPK 8
#define TW (N_EXP*EW)
#define PAD_SLOTS 20480   // 16384 + 64*63 rounded up to 64-tile granularity
#define SCHED_MAX 2560    // 8 * 320 worst-case positions, mult of 512
#define OUT_BASE (2048*768)

typedef __attribute__((ext_vector_type(8))) short bf16x8;
typedef __attribute__((ext_vector_type(4))) float f32x4;

typedef __attribute__((address_space(1))) void GAS;
typedef __attribute__((address_space(3))) void LAS;
#define GLOAD16(g, l) __builtin_amdgcn_global_load_lds((GAS*)(g), (LAS*)(l), 16, 0, 0)

__device__ inline unsigned short f2bu(float f) {
  union { __hip_bfloat16 b; unsigned short u; } cv; cv.b = __float2bfloat16(f); return cv.u;
}
__device__ inline unsigned int pk2(float a, float b) {
  return (unsigned int)f2bu(a) | ((unsigned int)f2bu(b) << 16);
}

// ---------------- init ----------------
__global__ void k_init(int* counts, int* cursor, float* psum, float* scal,
                       float* wgt_slot, int* tok_slot, int* sched_e) {
  int i = blockIdx.x*256 + threadIdx.x;   // 20480 threads
  if (i < N_EXP) { counts[i] = 0; cursor[i] = 0; psum[i] = 0.f; }
  if (i < 2) scal[i] = 0.f;
  if (i < PAD_SLOTS) { wgt_slot[i] = 0.f; tok_slot[i] = 0; }
  if (i < SCHED_MAX) sched_e[i] = -1;
}

// ---------------- router logits GEMM: lp[kc][t][e] partial sums ----------------
__global__ __launch_bounds__(256) void k_logits(const float* __restrict__ x,
                                                const float* __restrict__ rw,
                                                float* __restrict__ lp) {
  __shared__ float rw_s[8][256];
  int tid = threadIdx.x;
  int tg = blockIdx.x, eg = blockIdx.y, kc = blockIdx.z;
  #pragma unroll
  for (int idx = 0; idx < 8; idx++)
    rw_s[idx][tid] = rw[(size_t)(eg*8 + idx)*D_EMBD + kc*256 + tid];
  __syncthreads();
  int tok = tg*256 + tid;
  const float4* x4 = reinterpret_cast<const float4*>(x + (size_t)tok*D_EMBD + kc*256);
  float acc[8];
  #pragma unroll
  for (int e = 0; e < 8; e++) acc[e] = 0.f;
  #pragma unroll 4
  for (int k4 = 0; k4 < 64; k4++) {
    float4 xv = x4[k4];
    #pragma unroll
    for (int e = 0; e < 8; e++)
      acc[e] += xv.x*rw_s[e][k4*4+0] + xv.y*rw_s[e][k4*4+1]
              + xv.z*rw_s[e][k4*4+2] + xv.w*rw_s[e][k4*4+3];
  }
  float* dst = lp + (size_t)kc*T_TOKENS*N_EXP + (size_t)tok*N_EXP + eg*8;
  float4 o0 = {acc[0], acc[1], acc[2], acc[3]};
  float4 o1 = {acc[4], acc[5], acc[6], acc[7]};
  reinterpret_cast<float4*>(dst)[0] = o0;
  reinterpret_cast<float4*>(dst)[1] = o1;
}

// ---------------- router part 2: sigmoid, parallel-rank top-8, losses ----------------
__global__ __launch_bounds__(256) void k_router2(const float* __restrict__ lp,
                          int* __restrict__ sel_e, float* __restrict__ sel_w,
                          int* __restrict__ counts, float* __restrict__ psum,
                          float* __restrict__ scal) {
  __shared__ float psum_s[4][64];
  __shared__ int cnt_s[4][64];
  int tid = threadIdx.x, wv = tid >> 6, lane = tid & 63;
  float pacc = 0.f, zacc = 0.f;
  int cacc = 0;
  int tbase = blockIdx.x*8 + wv*2;
  #pragma unroll
  for (int it = 0; it < 2; it++) {
    int t = tbase + it;
    float logit = lp[(size_t)t*N_EXP + lane]
                + lp[(size_t)T_TOKENS*N_EXP + (size_t)t*N_EXP + lane]
                + lp[2*(size_t)T_TOKENS*N_EXP + (size_t)t*N_EXP + lane];
    float prob = 1.f/(1.f + expf(-logit));
    pacc += prob;
    float mx = logit;
    for (int s = 32; s; s >>= 1) mx = fmaxf(mx, __shfl_xor(mx, s, 64));
    float sse = expf(logit - mx);
    for (int s = 32; s; s >>= 1) sse += __shfl_xor(sse, s, 64);
    float lse = mx + logf(sse);
    zacc += lse*lse;
    int rank = 0;
    #pragma unroll
    for (int j = 0; j < 64; j++) {
      float pj = __shfl(prob, j, 64);
      rank += (pj > prob || (pj == prob && j < lane)) ? 1 : 0;
    }
    bool sel = rank < TOPK;
    float sp = sel ? prob : 0.f;
    for (int s = 32; s; s >>= 1) sp += __shfl_xor(sp, s, 64);
    if (sel) {
      sel_e[t*TOPK + rank] = lane;
      sel_w[t*TOPK + rank] = prob / (sp + 1e-20f);
      cacc++;
    }
  }
  psum_s[wv][lane] = pacc;
  cnt_s[wv][lane] = cacc;
  if (lane == 0) atomicAdd(&scal[0], zacc);
  __syncthreads();
  if (tid < 64) {
    float p = psum_s[0][tid] + psum_s[1][tid] + psum_s[2][tid] + psum_s[3][tid];
    int c = cnt_s[0][tid] + cnt_s[1][tid] + cnt_s[2][tid] + cnt_s[3][tid];
    atomicAdd(&psum[tid], p);
    atomicAdd(&counts[tid], c);
  }
}

// ---------------- schedule: 64-row tiles, XCD-grouped positions ----------------
__global__ void k_schedule(const int* __restrict__ counts, int* __restrict__ offsets,
                           int* __restrict__ sched_e, int* __restrict__ sched_r0) {
  int e = threadIdx.x;   // 64 threads, one wave
  int c = counts[e];
  int tiles = (c + 63) >> 6;
  int padded = tiles << 6;
  int ip = padded;
  for (int s = 1; s < 64; s <<= 1) { int v = __shfl_up(ip, s, 64); if (e >= s) ip += v; }
  int rowoff = ip - padded;
  offsets[e] = rowoff;
  int it = tiles;
  for (int s = 8; s < 64; s <<= 1) { int v = __shfl_up(it, s, 64); if (e >= s) it += v; }
  int rank = it - tiles;
  int xcd = e & 7;
  for (int i = 0; i < tiles; i++) {
    int p = xcd + 8*(rank + i);
    sched_e[p] = e;
    sched_r0[p] = rowoff + i*64;
  }
}

// ---------------- assign tokens to slots ----------------
__global__ void k_assign(const int* __restrict__ sel_e, const float* __restrict__ sel_w,
                         const int* __restrict__ offsets, int* __restrict__ cursor,
                         int* __restrict__ tok_slot, float* __restrict__ wgt_slot,
                         int* __restrict__ slot_tk) {
  int i = blockIdx.x*256 + threadIdx.x;   // 16384
  int e = sel_e[i];
  int pos = atomicAdd(&cursor[e], 1);
  int slot = offsets[e] + pos;
  tok_slot[slot] = i >> 3;
  wgt_slot[slot] = sel_w[i];
  slot_tk[i] = slot;
}

// ---------------- grouped GEMM with fused fp32->bf16 convert+transpose staging ----------------
// 64x128 tile, BK=64, double-buffered.
// B staging (conflict-free): thread (n4=tid&31, kpb=tid>>5) loads 8 consecutive fp32
// k-rows of its col-quad, packs each col's 8 k's into one uint4, single b128 write to
// row n, chunk (kpb ^ S(n)), S(n) = (n&7)^((n>>3)&7). 2-way per 16-lane group = free.
template<int MODE>
__global__ __launch_bounds__(256) void k_moe_gemm(
    const void* __restrict__ Asrc, const float* __restrict__ Bsrc,
    const int* __restrict__ sched_e, const int* __restrict__ sched_r0,
    const int* __restrict__ tok_slot, const float* __restrict__ wgt_slot,
    __hip_bfloat16* __restrict__ outp) {
  constexpr int NS   = (MODE == 1) ? 12 : 4;       // K-steps of 64
  constexpr int BSTR = (MODE == 1) ? TW : D_EMBD;  // native B row stride (fp32)
  __shared__ __hip_bfloat16 As[2][64*64];
  __shared__ __hip_bfloat16 Bs[2][128*64];
  int tid = threadIdx.x;
  int nch = blockIdx.y;
  int n4 = tid & 31, kpb = tid >> 5;     // B staging: col-quad, k-octet
  int mrow = tid >> 4, k4f = tid & 15;   // A staging (MODE1)
  int arl = tid >> 3, akc = tid & 7;     // A gload (MODE2)
  int a_off = ((akc ^ (arl & 7)) << 3);
  int wv = tid >> 6, lane = tid & 63;
  int wm = wv >> 1, wn = wv & 1;
  int l15 = lane & 15, l4 = lane >> 4;

  for (int p = blockIdx.x; p < SCHED_MAX; p += gridDim.x) {
    int e = sched_e[p];
    if (e < 0) continue;
    int r0 = sched_r0[p];

    int browb = (MODE == 1) ? 0 : e*EW;                    // B k-row base
    int bcolb = (MODE == 1) ? (e*EW + nch*128) : nch*128;  // B col base

    int tks[4];
    size_t a_base0 = 0, a_base1 = 0;
    if (MODE == 1) {
      #pragma unroll
      for (int i = 0; i < 4; i++) tks[i] = tok_slot[r0 + i*16 + mrow];
    } else {
      a_base0 = (size_t)(r0 + arl) * EW;
      a_base1 = (size_t)(r0 + arl + 32) * EW;
    }

    float bv[8][4], av[4][4];

    auto B_LOAD = [&](int k0) {
      const float* rp = Bsrc + (size_t)(browb + k0 + kpb*8)*BSTR + bcolb + n4*4;
      #pragma unroll
      for (int r = 0; r < 8; r++)
        *reinterpret_cast<float4*>(&bv[r][0]) =
            *reinterpret_cast<const float4*>(rp + (size_t)r*BSTR);
    };
    auto B_WRITE = [&](int bsel) {
      char* bs = (char*)&Bs[bsel][0];
      #pragma unroll
      for (int c = 0; c < 4; c++) {
        int n = n4*4 + c;
        int ch = kpb ^ ((n & 7) ^ ((n >> 3) & 7));
        uint4 o = { pk2(bv[0][c], bv[1][c]), pk2(bv[2][c], bv[3][c]),
                    pk2(bv[4][c], bv[5][c]), pk2(bv[6][c], bv[7][c]) };
        *reinterpret_cast<uint4*>(bs + n*128 + ch*16) = o;
      }
    };
    auto A_LOAD1 = [&](int k0) {
      const float* xf = (const float*)Asrc;
      #pragma unroll
      for (int i = 0; i < 4; i++)
        *reinterpret_cast<float4*>(&av[i][0]) =
            *reinterpret_cast<const float4*>(xf + (size_t)tks[i]*D_EMBD + k0 + k4f*4);
    };
    auto A_WRITE1 = [&](int bsel) {
      char* as_ = (char*)&As[bsel][0];
      #pragma unroll
      for (int i = 0; i < 4; i++) {
        int m = i*16 + mrow;
        int ch = (k4f >> 1) ^ (m & 7);
        uint2 val = { pk2(av[i][0], av[i][1]), pk2(av[i][2], av[i][3]) };
        *reinterpret_cast<uint2*>(as_ + m*128 + ch*16 + (k4f & 1)*8) = val;
      }
    };
    auto A_GLOAD2 = [&](int bsel, int k0) {
      const __hip_bfloat16* hb = (const __hip_bfloat16*)Asrc;
      GLOAD16(hb + a_base0 + k0 + a_off, &As[bsel][0] + tid*8);
      GLOAD16(hb + a_base1 + k0 + a_off, &As[bsel][0] + (256 + tid)*8);
    };

    f32x4 acc[2][4];
    f32x4 z = {0.f, 0.f, 0.f, 0.f};
    #pragma unroll
    for (int m = 0; m < 2; m++)
      #pragma unroll
      for (int n = 0; n < 4; n++) acc[m][n] = z;

    // prologue: stage step 0 into buf 0
    if (MODE == 1) { A_LOAD1(0); B_LOAD(0); A_WRITE1(0); B_WRITE(0); }
    else           { A_GLOAD2(0, 0); B_LOAD(0); B_WRITE(0);
                     asm volatile("s_waitcnt vmcnt(0)" ::: "memory"); }
    __syncthreads();

    int cur = 0;
    for (int step = 0; step < NS; step++) {
      bool more = (step + 1 < NS);
      int k1 = (step + 1)*64;
      if (more) {
        if (MODE == 1) { A_LOAD1(k1); B_LOAD(k1); }
        else           { A_GLOAD2(cur ^ 1, k1); B_LOAD(k1); }
      }
      const char* asC = (const char*)&As[cur][0];
      const char* bsC = (const char*)&Bs[cur][0];
      bf16x8 af[2][2], bq[4][2];
      #pragma unroll
      for (int m = 0; m < 2; m++) {
        int ra = wm*32 + m*16 + l15;
        #pragma unroll
        for (int kk = 0; kk < 2; kk++)
          af[m][kk] = *reinterpret_cast<const bf16x8*>(
              asC + ra*128 + (((kk*4 + l4) ^ (ra & 7)) << 4));
      }
      #pragma unroll
      for (int n = 0; n < 4; n++) {
        int rb = wn*64 + n*16 + l15;
        int Sb = (rb & 7) ^ ((rb >> 3) & 7);
        #pragma unroll
        for (int kk = 0; kk < 2; kk++)
          bq[n][kk] = *reinterpret_cast<const bf16x8*>(
              bsC + rb*128 + (((kk*4 + l4) ^ Sb) << 4));
      }
      #pragma unroll
      for (int kk = 0; kk < 2; kk++)
        #pragma unroll
        for (int m = 0; m < 2; m++)
          #pragma unroll
          for (int n = 0; n < 4; n++)
            acc[m][n] = __builtin_amdgcn_mfma_f32_16x16x32_bf16(af[m][kk], bq[n][kk], acc[m][n], 0, 0, 0);
      if (more) {
        if (MODE == 1) { A_WRITE1(cur ^ 1); B_WRITE(cur ^ 1); }
        else           { B_WRITE(cur ^ 1);
                         asm volatile("s_waitcnt vmcnt(0)" ::: "memory"); }
      }
      __syncthreads();
      cur ^= 1;
    }

    if (MODE == 1) {
      #pragma unroll
      for (int m = 0; m < 2; m++)
        #pragma unroll
        for (int j = 0; j < 4; j++) {
          int r = r0 + wm*32 + m*16 + l4*4 + j;
          float wg = wgt_slot[r];
          #pragma unroll
          for (int n = 0; n < 4; n++) {
            int col = nch*128 + wn*64 + n*16 + l15;
            float v = fmaxf(acc[m][n][j], 0.f);
            outp[(size_t)r*EW + col] = __float2bfloat16(v*v*wg);
          }
        }
    } else {
      #pragma unroll
      for (int m = 0; m < 2; m++)
        #pragma unroll
        for (int j = 0; j < 4; j++) {
          int r = r0 + wm*32 + m*16 + l4*4 + j;
          #pragma unroll
          for (int n = 0; n < 4; n++) {
            int col = nch*128 + wn*64 + n*16 + l15;
            outp[(size_t)r*D_EMBD + col] = __float2bfloat16(acc[m][n][j]);
          }
        }
    }
  }
}

// ---------------- combine 8 expert rows per token (vectorized gather) ----------------
__global__ void k_combine(const __hip_bfloat16* __restrict__ y, const int* __restrict__ slot_tk,
                          float* __restrict__ out) {
  __shared__ int s[TOPK];
  int t = blockIdx.x, tid = threadIdx.x;
  if (tid < TOPK) s[tid] = slot_tk[t*TOPK + tid];
  __syncthreads();
  if (tid < 192) {
    int c = tid*4;
    float a0 = 0.f, a1 = 0.f, a2 = 0.f, a3 = 0.f;
    #pragma unroll
    for (int k = 0; k < TOPK; k++) {
      ushort4 v = *reinterpret_cast<const ushort4*>(&y[(size_t)s[k]*D_EMBD + c]);
      union { unsigned int u; float f; } f0, f1, f2, f3;
      f0.u = ((unsigned int)v.x) << 16;
      f1.u = ((unsigned int)v.y) << 16;
      f2.u = ((unsigned int)v.z) << 16;
      f3.u = ((unsigned int)v.w) << 16;
      a0 += f0.f; a1 += f1.f; a2 += f2.f; a3 += f3.f;
    }
    float4 o = {a0, a1, a2, a3};
    *reinterpret_cast<float4*>(&out[(size_t)t*D_EMBD + c]) = o;
  }
}

// ---------------- aux losses + f_i ----------------
__global__ void k_finalize(const int* __restrict__ counts, const float* __restrict__ psum,
                           const float* __restrict__ scal, float* __restrict__ out) {
  __shared__ float part[N_EXP], ptot[N_EXP];
  int e = threadIdx.x;
  float f = (float)counts[e] / 16384.f;
  float p = psum[e] / 2048.f;
  part[e] = f * p;
  ptot[e] = p;
  out[OUT_BASE + 3 + e] = f;
  __syncthreads();
  if (e == 0) {
    float s = 0.f, q = 0.f;
    for (int i = 0; i < N_EXP; i++) { s += part[i]; q += ptot[i]; }
    out[OUT_BASE + 0] = scal[0] / 2048.f;      // router_z_loss
    out[OUT_BASE + 1] = 64.f * s;              // load_balance_loss
    out[OUT_BASE + 2] = q;                     // compute_loss
  }
}

extern "C" void kernel_launch(void* const* d_in, const int* in_sizes, int n_in,
                              void* d_out, int out_size, void* d_ws, size_t ws_size,
                              hipStream_t stream) {
  const float* x  = (const float*)d_in[0];
  const float* rw = (const float*)d_in[1];
  const float* w1 = (const float*)d_in[2];
  const float* w2 = (const float*)d_in[3];
  float* out = (float*)d_out;
  char* ws = (char*)d_ws;

  size_t o = 0;
  auto alloc = [&](size_t b) { size_t r = o; o += (b + 255) & ~(size_t)255; return r; };
  __hip_bfloat16* hprm  = (__hip_bfloat16*)(ws + alloc((size_t)PAD_SLOTS*256*2));
  __hip_bfloat16* yprm  = (__hip_bfloat16*)(ws + alloc((size_t)PAD_SLOTS*768*2));
  float* lp      = (float*)(ws + alloc(3UL*2048*64*4));
  int*   sel_e   = (int*)  (ws + alloc(16384UL*4));
  float* sel_w   = (float*)(ws + alloc(16384UL*4));
  int*   slot_tk = (int*)  (ws + alloc(16384UL*4));
  int*   tokslot = (int*)  (ws + alloc((size_t)PAD_SLOTS*4));
  float* wgtslot = (float*)(ws + alloc((size_t)PAD_SLOTS*4));
  int*   counts  = (int*)  (ws + alloc(256));
  int*   cursor  = (int*)  (ws + alloc(256));
  float* psum    = (float*)(ws + alloc(256));
  float* scal    = (float*)(ws + alloc(256));
  int*   offsets = (int*)  (ws + alloc(256));
  int*   sch_e   = (int*)  (ws + alloc(SCHED_MAX*4));
  int*   sch_r0  = (int*)  (ws + alloc(SCHED_MAX*4));

  k_init<<<80, 256, 0, stream>>>(counts, cursor, psum, scal, wgtslot, tokslot, sch_e);
  k_logits<<<dim3(8, 8, 3), 256, 0, stream>>>(x, rw, lp);
  k_router2<<<256, 256, 0, stream>>>(lp, sel_e, sel_w, counts, psum, scal);
  k_schedule<<<1, 64, 0, stream>>>(counts, offsets, sch_e, sch_r0);
  k_assign<<<64, 256, 0, stream>>>(sel_e, sel_w, offsets, cursor, tokslot, wgtslot, slot_tk);
  k_moe_gemm<1><<<dim3(512, 2), 256, 0, stream>>>((const void*)x, w1, sch_e, sch_r0, tokslot, wgtslot, hprm);
  k_moe_gemm<2><<<dim3(512, 6), 256, 0, stream>>>((const void*)hprm, w2, sch_e, sch_r0, tokslot, wgtslot, yprm);
  k_combine<<<2048, 256, 0, stream>>>(yprm, slot_tk, out);
  k_finalize<<<1, 64, 0, stream>>>(counts, psum, scal, out);
}